// Round 1
// baseline (961.674 us; speedup 1.0000x reference)
//
#include <hip/hip_runtime.h>
#include <hip/hip_bf16.h>
#include <cmath>
#include <cstdint>

// AttentionPoolingAggregator — MI355X fp32 round 1 (correctness + profile baseline)
//
// Pipeline:
//   K0 zero counts          K4 gemm company_proj = company_x @ W_company^T
//   K1 histogram dst        K5 gemm news_proj    = news_x    @ W_news^T
//   K2 exclusive scan       K6 per-company scores + stable softmax (no atomics)
//   K3 CSR bucket fill      K7 per-company weighted aggregation (coalesced rows)
//
// Workspace: news_proj 204.8MB + company_proj 10.2MB + weights/srcs_sorted 5.1MB
//            + counts/offsets/cursor ~0.12MB  (~220MB total)

#define H 256

// ---------------- CSR build ----------------
__global__ void zero_counts_kernel(int* __restrict__ counts, int C) {
  int i = blockIdx.x * blockDim.x + threadIdx.x;
  if (i < C) counts[i] = 0;
}

__global__ void count_kernel(const int* __restrict__ dst, int* __restrict__ counts, int E) {
  int e = blockIdx.x * blockDim.x + threadIdx.x;
  if (e < E) atomicAdd(&counts[dst[e]], 1);
}

// single-block scan over C counts -> exclusive offsets[0..C], cursor copy
__global__ void scan_kernel(const int* __restrict__ counts, int* __restrict__ offsets,
                            int* __restrict__ cursor, int C) {
  __shared__ int wsum[4];
  int tid = threadIdx.x;
  int lane = tid & 63, wid = tid >> 6;
  int base = 0;
  for (int start = 0; start < C; start += 256) {
    int idx = start + tid;
    int val = (idx < C) ? counts[idx] : 0;
    int x = val;
#pragma unroll
    for (int off = 1; off < 64; off <<= 1) {
      int y = __shfl_up(x, off);
      if (lane >= off) x += y;
    }
    if (lane == 63) wsum[wid] = x;
    __syncthreads();
    int add = base;
    for (int w = 0; w < wid; ++w) add += wsum[w];
    if (idx < C) {
      int excl = add + x - val;
      offsets[idx] = excl;
      cursor[idx]  = excl;
    }
    int tot = wsum[0] + wsum[1] + wsum[2] + wsum[3];
    __syncthreads();
    base += tot;
  }
  if (tid == 0) offsets[C] = base;
}

__global__ void fill_kernel(const int* __restrict__ src, const int* __restrict__ dst,
                            int* __restrict__ cursor, int* __restrict__ srcs_sorted, int E) {
  int e = blockIdx.x * blockDim.x + threadIdx.x;
  if (e < E) {
    int d = dst[e];
    int pos = atomicAdd(&cursor[d], 1);
    srcs_sorted[pos] = src[e];
  }
}

// ---------------- GEMM: out[m][n] = sum_k X[m][k] * W[n][k]  (K = N = 256) ----------------
// 64x64 tile per block, 256 threads, 4x4 micro-tile, k-major LDS -> ds_read_b128 fragments.
__global__ __launch_bounds__(256) void gemm_xwt_kernel(const float* __restrict__ X,
                                                       const float* __restrict__ W,
                                                       float* __restrict__ out, int M) {
  __shared__ float Xs[32][68];  // [k][m], pad 68 keeps float4 reads 16B-aligned
  __shared__ float Ws[32][68];  // [k][n]
  const int tid = threadIdx.x;
  const int row0 = blockIdx.x * 64, col0 = blockIdx.y * 64;
  const int tn = tid & 15, tm = tid >> 4;
  float acc[4][4] = {{0.f, 0.f, 0.f, 0.f}, {0.f, 0.f, 0.f, 0.f},
                     {0.f, 0.f, 0.f, 0.f}, {0.f, 0.f, 0.f, 0.f}};
  for (int k0 = 0; k0 < H; k0 += 32) {
#pragma unroll
    for (int l = 0; l < 2; ++l) {
      int idx = tid * 2 + l;          // 0..511
      int r = idx >> 3, c4 = idx & 7; // r: tile row 0..63, c4: float4 col 0..7
      int gr = row0 + r; if (gr >= M) gr = M - 1;  // clamp; stores are guarded
      const float4 xv = *(const float4*)(X + (size_t)gr * H + k0 + c4 * 4);
      Xs[c4 * 4 + 0][r] = xv.x; Xs[c4 * 4 + 1][r] = xv.y;
      Xs[c4 * 4 + 2][r] = xv.z; Xs[c4 * 4 + 3][r] = xv.w;
      int gw = col0 + r;  // always < 256
      const float4 wv = *(const float4*)(W + (size_t)gw * H + k0 + c4 * 4);
      Ws[c4 * 4 + 0][r] = wv.x; Ws[c4 * 4 + 1][r] = wv.y;
      Ws[c4 * 4 + 2][r] = wv.z; Ws[c4 * 4 + 3][r] = wv.w;
    }
    __syncthreads();
#pragma unroll
    for (int k = 0; k < 32; ++k) {
      const float4 a = *(const float4*)&Xs[k][tm * 4];
      const float4 b = *(const float4*)&Ws[k][tn * 4];
      acc[0][0] += a.x * b.x; acc[0][1] += a.x * b.y; acc[0][2] += a.x * b.z; acc[0][3] += a.x * b.w;
      acc[1][0] += a.y * b.x; acc[1][1] += a.y * b.y; acc[1][2] += a.y * b.z; acc[1][3] += a.y * b.w;
      acc[2][0] += a.z * b.x; acc[2][1] += a.z * b.y; acc[2][2] += a.z * b.z; acc[2][3] += a.z * b.w;
      acc[3][0] += a.w * b.x; acc[3][1] += a.w * b.y; acc[3][2] += a.w * b.z; acc[3][3] += a.w * b.w;
    }
    __syncthreads();
  }
#pragma unroll
  for (int i = 0; i < 4; ++i) {
    int gr = row0 + tm * 4 + i;
    if (gr < M) {
      float4 o = make_float4(acc[i][0], acc[i][1], acc[i][2], acc[i][3]);
      *(float4*)(out + (size_t)gr * H + col0 + tn * 4) = o;
    }
  }
}

// ---------------- per-company scores + softmax ----------------
__device__ __forceinline__ float fast_tanh(float x) {
  float e = __expf(2.f * x);       // inf/0 at extremes -> correct +/-1 limits
  return 1.f - 2.f / (e + 1.f);
}

__global__ __launch_bounds__(256) void scores_kernel(
    const float* __restrict__ news_proj, const float* __restrict__ company_proj,
    const float* __restrict__ v, const int* __restrict__ offsets,
    const int* __restrict__ srcs_sorted, float* __restrict__ wsorted) {
  const int c = blockIdx.x;
  const int tid = threadIdx.x, lane = tid & 63, wid = tid >> 6;
  __shared__ float cp[H];
  __shared__ float redmax[4];
  __shared__ float redsum[4];
  cp[tid] = company_proj[(size_t)c * H + tid];
  __syncthreads();
  const float4 vv = *(const float4*)(v + lane * 4);
  const float4 cq = *(const float4*)&cp[lane * 4];
  const int beg = offsets[c], end = offsets[c + 1];

  // pass 1: one wave per edge; 256-elem tanh-dot, wave reduce
  float lmax = -INFINITY;
  for (int i = beg + wid; i < end; i += 4) {
    int s = srcs_sorted[i];
    const float4 p = *(const float4*)(news_proj + (size_t)s * H + lane * 4);
    float t0 = fast_tanh(p.x + cq.x);
    float t1 = fast_tanh(p.y + cq.y);
    float t2 = fast_tanh(p.z + cq.z);
    float t3 = fast_tanh(p.w + cq.w);
    float partial = t0 * vv.x + t1 * vv.y + t2 * vv.z + t3 * vv.w;
#pragma unroll
    for (int off = 32; off > 0; off >>= 1) partial += __shfl_xor(partial, off);
    if (lane == 0) wsorted[i] = partial;
    lmax = fmaxf(lmax, partial);
  }
  if (lane == 0) redmax[wid] = lmax;
  __syncthreads();  // also makes pass-1 global writes visible block-wide
  const float smax = fmaxf(fmaxf(redmax[0], redmax[1]), fmaxf(redmax[2], redmax[3]));

  // pass 2: exp + sum
  float psum = 0.f;
  for (int i = beg + tid; i < end; i += 256) {
    float w = __expf(wsorted[i] - smax);
    wsorted[i] = w;
    psum += w;
  }
#pragma unroll
  for (int off = 32; off > 0; off >>= 1) psum += __shfl_xor(psum, off);
  if (lane == 0) redsum[wid] = psum;
  __syncthreads();
  const float denom = redsum[0] + redsum[1] + redsum[2] + redsum[3];
  const float rden = 1.f / fmaxf(denom, 1e-9f);

  // pass 3: normalize (same thread that wrote in pass 2 rewrites -> no extra sync)
  for (int i = beg + tid; i < end; i += 256) wsorted[i] *= rden;
}

// ---------------- per-company weighted aggregation ----------------
__global__ __launch_bounds__(256) void aggregate_kernel(
    const float* __restrict__ news_x, const int* __restrict__ offsets,
    const int* __restrict__ srcs_sorted, const float* __restrict__ wsorted,
    float* __restrict__ out) {
  const int c = blockIdx.x, t = threadIdx.x;
  const int beg = offsets[c], end = offsets[c + 1];
  float acc0 = 0.f, acc1 = 0.f;
  int i = beg;
  for (; i + 2 <= end; i += 2) {  // unroll-2: two independent load chains
    int s0 = srcs_sorted[i], s1 = srcs_sorted[i + 1];
    float w0 = wsorted[i], w1 = wsorted[i + 1];
    acc0 = fmaf(w0, news_x[(size_t)s0 * H + t], acc0);
    acc1 = fmaf(w1, news_x[(size_t)s1 * H + t], acc1);
  }
  if (i < end)
    acc0 = fmaf(wsorted[i], news_x[(size_t)srcs_sorted[i] * H + t], acc0);
  out[(size_t)c * H + t] = acc0 + acc1;  // zero-edge companies get 0
}

// ---------------- launch ----------------
extern "C" void kernel_launch(void* const* d_in, const int* in_sizes, int n_in,
                              void* d_out, int out_size, void* d_ws, size_t ws_size,
                              hipStream_t stream) {
  const float* news_x    = (const float*)d_in[0];
  const float* company_x = (const float*)d_in[1];
  const float* W_news    = (const float*)d_in[2];
  const float* W_company = (const float*)d_in[3];
  const float* v         = (const float*)d_in[4];
  const int*   src       = (const int*)d_in[5];
  const int*   dst       = (const int*)d_in[6];
  const int N = in_sizes[0] / H;
  const int C = in_sizes[1] / H;
  const int E = in_sizes[5];
  float* out = (float*)d_out;

  char* p = (char*)d_ws;
  float* news_proj    = (float*)p; p += (size_t)N * H * sizeof(float);
  float* company_proj = (float*)p; p += (size_t)C * H * sizeof(float);
  float* wsorted      = (float*)p; p += (size_t)E * sizeof(float);
  int*   srcs_sorted  = (int*)p;   p += (size_t)E * sizeof(int);
  int*   counts       = (int*)p;   p += (size_t)C * sizeof(int);
  int*   offsets      = (int*)p;   p += (size_t)(C + 1) * sizeof(int);
  int*   cursor       = (int*)p;   p += (size_t)C * sizeof(int);

  zero_counts_kernel<<<(C + 255) / 256, 256, 0, stream>>>(counts, C);
  count_kernel<<<(E + 255) / 256, 256, 0, stream>>>(dst, counts, E);
  scan_kernel<<<1, 256, 0, stream>>>(counts, offsets, cursor, C);
  fill_kernel<<<(E + 255) / 256, 256, 0, stream>>>(src, dst, cursor, srcs_sorted, E);

  gemm_xwt_kernel<<<dim3((C + 63) / 64, 4), 256, 0, stream>>>(company_x, W_company, company_proj, C);
  gemm_xwt_kernel<<<dim3((N + 63) / 64, 4), 256, 0, stream>>>(news_x, W_news, news_proj, N);

  scores_kernel<<<C, 256, 0, stream>>>(news_proj, company_proj, v, offsets, srcs_sorted, wsorted);
  aggregate_kernel<<<C, 256, 0, stream>>>(news_x, offsets, srcs_sorted, wsorted, out);
}

// Round 2
// 768.433 us; speedup vs baseline: 1.2515x; 1.2515x over previous
//
#include <hip/hip_runtime.h>
#include <hip/hip_bf16.h>
#include <cmath>
#include <cstdint>

// AttentionPoolingAggregator — MI355X round 2
// GEMMs moved to bf16 MFMA: X in bf16 (1 product), W split hi+lo bf16 (2 products)
// => near-fp32 weight precision at 2x bf16-MFMA cost, X fetched once per row.
//
// Pipeline:
//   K0 zero counts        K4 wsplit (W_news, W_company -> bf16 hi/lo, once each)
//   K1 histogram dst      K5 mfma gemm company_proj / news_proj (fp32 out)
//   K2 exclusive scan     K6 per-company scores + stable softmax (no atomics)
//   K3 CSR bucket fill    K7 per-company weighted aggregation (coalesced rows)

#define H 256

typedef __attribute__((ext_vector_type(8))) short bfrag;  // 8 bf16 (4 VGPRs)
typedef __attribute__((ext_vector_type(4))) float ffrag;  // 4 fp32 acc

__device__ __forceinline__ ushort f2bf(float f) {  // fp32 -> bf16 RNE
  uint u = __float_as_uint(f);
  uint r = u + 0x7FFFu + ((u >> 16) & 1u);
  return (ushort)(r >> 16);
}
__device__ __forceinline__ float bf2f(ushort h) {
  return __uint_as_float((uint)h << 16);
}

// ---------------- CSR build ----------------
__global__ void zero_counts_kernel(int* __restrict__ counts, int C) {
  int i = blockIdx.x * blockDim.x + threadIdx.x;
  if (i < C) counts[i] = 0;
}

__global__ void count_kernel(const int* __restrict__ dst, int* __restrict__ counts, int E) {
  int e = blockIdx.x * blockDim.x + threadIdx.x;
  if (e < E) atomicAdd(&counts[dst[e]], 1);
}

__global__ void scan_kernel(const int* __restrict__ counts, int* __restrict__ offsets,
                            int* __restrict__ cursor, int C) {
  __shared__ int wsum[4];
  int tid = threadIdx.x;
  int lane = tid & 63, wid = tid >> 6;
  int base = 0;
  for (int start = 0; start < C; start += 256) {
    int idx = start + tid;
    int val = (idx < C) ? counts[idx] : 0;
    int x = val;
#pragma unroll
    for (int off = 1; off < 64; off <<= 1) {
      int y = __shfl_up(x, off);
      if (lane >= off) x += y;
    }
    if (lane == 63) wsum[wid] = x;
    __syncthreads();
    int add = base;
    for (int w = 0; w < wid; ++w) add += wsum[w];
    if (idx < C) {
      int excl = add + x - val;
      offsets[idx] = excl;
      cursor[idx]  = excl;
    }
    int tot = wsum[0] + wsum[1] + wsum[2] + wsum[3];
    __syncthreads();
    base += tot;
  }
  if (tid == 0) offsets[C] = base;
}

__global__ void fill_kernel(const int* __restrict__ src, const int* __restrict__ dst,
                            int* __restrict__ cursor, int* __restrict__ srcs_sorted, int E) {
  int e = blockIdx.x * blockDim.x + threadIdx.x;
  if (e < E) {
    int d = dst[e];
    int pos = atomicAdd(&cursor[d], 1);
    srcs_sorted[pos] = src[e];
  }
}

// ---------------- W split: fp32[256][256] -> bf16 hi + bf16 lo ----------------
__global__ void wsplit_kernel(const float* __restrict__ W,
                              ushort* __restrict__ hi, ushort* __restrict__ lo) {
  int i = blockIdx.x * 256 + threadIdx.x;  // 65536 elements
  float w = W[i];
  ushort h = f2bf(w);
  hi[i] = h;
  lo[i] = f2bf(w - bf2f(h));
}

// ---------------- MFMA GEMM: out[m][n] = sum_k X[m][k]*W[n][k] ----------------
// Block: 256 thr (4 waves), tile M=64 x N=256 (full), K=256 in 8 steps of 32.
// Wave w owns n in [64w, 64w+64): 4 mtiles x 4 ntiles of 16x16x32 MFMA.
// X staged to LDS as bf16 (pitch 40 = 16B-aligned frags, ~2-way banks = free).
// W hi/lo fragments read straight from global (256KB, L2-resident).
__global__ __launch_bounds__(256) void gemm_mfma_kernel(
    const float* __restrict__ X, const ushort* __restrict__ Whi,
    const ushort* __restrict__ Wlo, float* __restrict__ out, int M) {
  constexpr int PITCH = 40;  // ushorts per LDS row (80B: 16B-aligned, bank-friendly)
  __shared__ ushort Xs[64 * PITCH];
  const int tid = threadIdx.x;
  const int wave = tid >> 6, lane = tid & 63;
  const int q = lane >> 4, nidx = lane & 15;  // quad (k-offset), n-in-tile
  const int row0 = blockIdx.x * 64;
  const int srow = tid >> 2, skc = tid & 3;   // staging: row, 8-float chunk

  ffrag acc[4][4];
#pragma unroll
  for (int i = 0; i < 4; ++i)
#pragma unroll
    for (int t = 0; t < 4; ++t) acc[i][t] = (ffrag)(0.f);

  int gr = row0 + srow;
  if (gr >= M) gr = M - 1;  // clamp loads; stores guarded
  const float* xrow = X + (size_t)gr * H + skc * 8;

  for (int k0 = 0; k0 < H; k0 += 32) {
    // ---- stage X tile (64 x 32 fp32 -> bf16 LDS) ----
    const float4 x0 = *(const float4*)(xrow + k0);
    const float4 x1 = *(const float4*)(xrow + k0 + 4);
    bfrag xb;
    xb[0] = (short)f2bf(x0.x); xb[1] = (short)f2bf(x0.y);
    xb[2] = (short)f2bf(x0.z); xb[3] = (short)f2bf(x0.w);
    xb[4] = (short)f2bf(x1.x); xb[5] = (short)f2bf(x1.y);
    xb[6] = (short)f2bf(x1.z); xb[7] = (short)f2bf(x1.w);
    *(bfrag*)&Xs[srow * PITCH + skc * 8] = xb;
    __syncthreads();

    // ---- B fragments from global (L2-hot): lane holds W[n][k0+q*8 .. +8) ----
    bfrag bhi[4], blo[4];
#pragma unroll
    for (int t = 0; t < 4; ++t) {
      const size_t off = (size_t)(wave * 64 + t * 16 + nidx) * H + k0 + q * 8;
      bhi[t] = *(const bfrag*)(Whi + off);
      blo[t] = *(const bfrag*)(Wlo + off);
    }
    // ---- A fragments from LDS: lane holds Xbf[16i+nidx][k0+q*8 .. +8) ----
    bfrag a[4];
#pragma unroll
    for (int i = 0; i < 4; ++i)
      a[i] = *(const bfrag*)&Xs[(16 * i + nidx) * PITCH + q * 8];

#pragma unroll
    for (int i = 0; i < 4; ++i)
#pragma unroll
      for (int t = 0; t < 4; ++t) {
        acc[i][t] = __builtin_amdgcn_mfma_f32_16x16x32_bf16(a[i], bhi[t], acc[i][t], 0, 0, 0);
        acc[i][t] = __builtin_amdgcn_mfma_f32_16x16x32_bf16(a[i], blo[t], acc[i][t], 0, 0, 0);
      }
    __syncthreads();
  }

  // ---- epilogue: C/D layout col=lane&15, row=q*4+reg ----
#pragma unroll
  for (int i = 0; i < 4; ++i) {
#pragma unroll
    for (int r = 0; r < 4; ++r) {
      const int grow = row0 + 16 * i + q * 4 + r;
      if (grow < M) {
#pragma unroll
        for (int t = 0; t < 4; ++t)
          out[(size_t)grow * H + wave * 64 + t * 16 + nidx] = acc[i][t][r];
      }
    }
  }
}

// ---------------- per-company scores + softmax ----------------
__device__ __forceinline__ float fast_tanh(float x) {
  float e = __expf(2.f * x);
  return 1.f - 2.f / (e + 1.f);
}

__global__ __launch_bounds__(256) void scores_kernel(
    const float* __restrict__ news_proj, const float* __restrict__ company_proj,
    const float* __restrict__ v, const int* __restrict__ offsets,
    const int* __restrict__ srcs_sorted, float* __restrict__ wsorted) {
  const int c = blockIdx.x;
  const int tid = threadIdx.x, lane = tid & 63, wid = tid >> 6;
  __shared__ float cp[H];
  __shared__ float redmax[4];
  __shared__ float redsum[4];
  cp[tid] = company_proj[(size_t)c * H + tid];
  __syncthreads();
  const float4 vv = *(const float4*)(v + lane * 4);
  const float4 cq = *(const float4*)&cp[lane * 4];
  const int beg = offsets[c], end = offsets[c + 1];

  float lmax = -INFINITY;
  for (int i = beg + wid; i < end; i += 4) {
    int s = srcs_sorted[i];
    const float4 p = *(const float4*)(news_proj + (size_t)s * H + lane * 4);
    float t0 = fast_tanh(p.x + cq.x);
    float t1 = fast_tanh(p.y + cq.y);
    float t2 = fast_tanh(p.z + cq.z);
    float t3 = fast_tanh(p.w + cq.w);
    float partial = t0 * vv.x + t1 * vv.y + t2 * vv.z + t3 * vv.w;
#pragma unroll
    for (int off = 32; off > 0; off >>= 1) partial += __shfl_xor(partial, off);
    if (lane == 0) wsorted[i] = partial;
    lmax = fmaxf(lmax, partial);
  }
  if (lane == 0) redmax[wid] = lmax;
  __syncthreads();
  const float smax = fmaxf(fmaxf(redmax[0], redmax[1]), fmaxf(redmax[2], redmax[3]));

  float psum = 0.f;
  for (int i = beg + tid; i < end; i += 256) {
    float w = __expf(wsorted[i] - smax);
    wsorted[i] = w;
    psum += w;
  }
#pragma unroll
  for (int off = 32; off > 0; off >>= 1) psum += __shfl_xor(psum, off);
  if (lane == 0) redsum[wid] = psum;
  __syncthreads();
  const float denom = redsum[0] + redsum[1] + redsum[2] + redsum[3];
  const float rden = 1.f / fmaxf(denom, 1e-9f);

  for (int i = beg + tid; i < end; i += 256) wsorted[i] *= rden;
}

// ---------------- per-company weighted aggregation ----------------
__global__ __launch_bounds__(256) void aggregate_kernel(
    const float* __restrict__ news_x, const int* __restrict__ offsets,
    const int* __restrict__ srcs_sorted, const float* __restrict__ wsorted,
    float* __restrict__ out) {
  const int c = blockIdx.x, t = threadIdx.x;
  const int beg = offsets[c], end = offsets[c + 1];
  float acc0 = 0.f, acc1 = 0.f;
  int i = beg;
  for (; i + 2 <= end; i += 2) {
    int s0 = srcs_sorted[i], s1 = srcs_sorted[i + 1];
    float w0 = wsorted[i], w1 = wsorted[i + 1];
    acc0 = fmaf(w0, news_x[(size_t)s0 * H + t], acc0);
    acc1 = fmaf(w1, news_x[(size_t)s1 * H + t], acc1);
  }
  if (i < end)
    acc0 = fmaf(wsorted[i], news_x[(size_t)srcs_sorted[i] * H + t], acc0);
  out[(size_t)c * H + t] = acc0 + acc1;
}

// ---------------- launch ----------------
extern "C" void kernel_launch(void* const* d_in, const int* in_sizes, int n_in,
                              void* d_out, int out_size, void* d_ws, size_t ws_size,
                              hipStream_t stream) {
  const float* news_x    = (const float*)d_in[0];
  const float* company_x = (const float*)d_in[1];
  const float* W_news    = (const float*)d_in[2];
  const float* W_company = (const float*)d_in[3];
  const float* v         = (const float*)d_in[4];
  const int*   src       = (const int*)d_in[5];
  const int*   dst       = (const int*)d_in[6];
  const int N = in_sizes[0] / H;
  const int C = in_sizes[1] / H;
  const int E = in_sizes[5];
  float* out = (float*)d_out;

  char* p = (char*)d_ws;
  float*  news_proj    = (float*)p;  p += (size_t)N * H * sizeof(float);
  float*  company_proj = (float*)p;  p += (size_t)C * H * sizeof(float);
  float*  wsorted      = (float*)p;  p += (size_t)E * sizeof(float);
  int*    srcs_sorted  = (int*)p;    p += (size_t)E * sizeof(int);
  int*    counts       = (int*)p;    p += (size_t)C * sizeof(int);
  int*    offsets      = (int*)p;    p += (size_t)(C + 1) * sizeof(int);
  int*    cursor       = (int*)p;    p += (size_t)C * sizeof(int);
  ushort* Wn_hi        = (ushort*)p; p += (size_t)H * H * sizeof(ushort);
  ushort* Wn_lo        = (ushort*)p; p += (size_t)H * H * sizeof(ushort);
  ushort* Wc_hi        = (ushort*)p; p += (size_t)H * H * sizeof(ushort);
  ushort* Wc_lo        = (ushort*)p; p += (size_t)H * H * sizeof(ushort);

  zero_counts_kernel<<<(C + 255) / 256, 256, 0, stream>>>(counts, C);
  count_kernel<<<(E + 255) / 256, 256, 0, stream>>>(dst, counts, E);
  scan_kernel<<<1, 256, 0, stream>>>(counts, offsets, cursor, C);
  fill_kernel<<<(E + 255) / 256, 256, 0, stream>>>(src, dst, cursor, srcs_sorted, E);

  wsplit_kernel<<<H * H / 256, 256, 0, stream>>>(W_company, Wc_hi, Wc_lo);
  wsplit_kernel<<<H * H / 256, 256, 0, stream>>>(W_news, Wn_hi, Wn_lo);

  gemm_mfma_kernel<<<(C + 63) / 64, 256, 0, stream>>>(company_x, Wc_hi, Wc_lo, company_proj, C);
  gemm_mfma_kernel<<<(N + 63) / 64, 256, 0, stream>>>(news_x, Wn_hi, Wn_lo, news_proj, N);

  scores_kernel<<<C, 256, 0, stream>>>(news_proj, company_proj, v, offsets, srcs_sorted, wsorted);
  aggregate_kernel<<<C, 256, 0, stream>>>(news_x, offsets, srcs_sorted, wsorted, out);
}

// Round 3
// 719.392 us; speedup vs baseline: 1.3368x; 1.0682x over previous
//
#include <hip/hip_runtime.h>
#include <hip/hip_bf16.h>
#include <cmath>
#include <cstdint>

// AttentionPoolingAggregator — MI355X round 3
//  * GEMM: whole-K X tile staged to LDS bf16 once (1 barrier), 8 barrier-free
//    k-steps, W hi/lo bf16 fragments straight from L2. Writes proj as bf16 and
//    (news only) the bf16-converted X table for the aggregate gather.
//  * Both gather tables bf16 => 204 MB combined, L3-resident; traffic halved.
//  * scores+softmax+aggregate fused into one per-company kernel.

#define H 256

typedef __attribute__((ext_vector_type(8))) short bfrag;  // 8 bf16 (4 VGPRs)
typedef __attribute__((ext_vector_type(4))) float ffrag;  // 4 fp32 acc

__device__ __forceinline__ ushort f2bf(float f) {  // fp32 -> bf16 RNE
  uint u = __float_as_uint(f);
  uint r = u + 0x7FFFu + ((u >> 16) & 1u);
  return (ushort)(r >> 16);
}
__device__ __forceinline__ float bf2f(ushort h) {
  return __uint_as_float((uint)h << 16);
}

// ---------------- CSR build ----------------
__global__ void zero_counts_kernel(int* __restrict__ counts, int C) {
  int i = blockIdx.x * blockDim.x + threadIdx.x;
  if (i < C) counts[i] = 0;
}

__global__ void count_kernel(const int* __restrict__ dst, int* __restrict__ counts, int E) {
  int e = blockIdx.x * blockDim.x + threadIdx.x;
  if (e < E) atomicAdd(&counts[dst[e]], 1);
}

__global__ void scan_kernel(const int* __restrict__ counts, int* __restrict__ offsets,
                            int* __restrict__ cursor, int C) {
  __shared__ int wsum[4];
  int tid = threadIdx.x;
  int lane = tid & 63, wid = tid >> 6;
  int base = 0;
  for (int start = 0; start < C; start += 256) {
    int idx = start + tid;
    int val = (idx < C) ? counts[idx] : 0;
    int x = val;
#pragma unroll
    for (int off = 1; off < 64; off <<= 1) {
      int y = __shfl_up(x, off);
      if (lane >= off) x += y;
    }
    if (lane == 63) wsum[wid] = x;
    __syncthreads();
    int add = base;
    for (int w = 0; w < wid; ++w) add += wsum[w];
    if (idx < C) {
      int excl = add + x - val;
      offsets[idx] = excl;
      cursor[idx]  = excl;
    }
    int tot = wsum[0] + wsum[1] + wsum[2] + wsum[3];
    __syncthreads();
    base += tot;
  }
  if (tid == 0) offsets[C] = base;
}

__global__ void fill_kernel(const int* __restrict__ src, const int* __restrict__ dst,
                            int* __restrict__ cursor, int* __restrict__ srcs_sorted, int E) {
  int e = blockIdx.x * blockDim.x + threadIdx.x;
  if (e < E) {
    int d = dst[e];
    int pos = atomicAdd(&cursor[d], 1);
    srcs_sorted[pos] = src[e];
  }
}

// ---------------- W split: fp32[256][256] -> bf16 hi + bf16 lo ----------------
__global__ void wsplit_kernel(const float* __restrict__ W,
                              ushort* __restrict__ hi, ushort* __restrict__ lo) {
  int i = blockIdx.x * 256 + threadIdx.x;
  float w = W[i];
  ushort h = f2bf(w);
  hi[i] = h;
  lo[i] = f2bf(w - bf2f(h));
}

// ---------------- MFMA GEMM: projbf[m][n] = bf16( sum_k X[m][k]*W[n][k] ) ----
// Block: 256 thr (4 waves), tile M=64 x N=256 (full), K=256.
// Whole X tile -> LDS bf16 (pitch 264: 16B-aligned frags, <=2-way banks=free),
// ONE barrier, then 8 straight-line k-steps (compiler pipelines B L2-loads
// across MFMAs). Optionally writes the bf16 X tile to global (xbf != null).
__global__ __launch_bounds__(256, 2) void gemm_mfma2(
    const float* __restrict__ X, const ushort* __restrict__ Whi,
    const ushort* __restrict__ Wlo, ushort* __restrict__ projbf,
    ushort* __restrict__ xbf, int M) {
  constexpr int PITCH = 264;           // ushorts per LDS row (528B = 33*16B)
  __shared__ ushort Xs[64 * PITCH];    // 33.8 KB
  const int tid = threadIdx.x;
  const int wave = tid >> 6, lane = tid & 63;
  const int q = lane >> 4, nidx = lane & 15;
  const int row0 = blockIdx.x * 64;

  // ---- stage whole 64x256 X tile (fp32 -> bf16), fully coalesced ----
#pragma unroll
  for (int it = 0; it < 8; ++it) {
    const int flat = it * 2048 + tid * 8;  // tile is contiguous 64KB in X
    const int r = flat >> 8, k = flat & 255;
    int gr = row0 + r;
    if (gr >= M) gr = M - 1;  // clamp: duplicate row, stores guarded/idempotent
    const float4 x0 = *(const float4*)(X + (size_t)gr * H + k);
    const float4 x1 = *(const float4*)(X + (size_t)gr * H + k + 4);
    bfrag xb;
    xb[0] = (short)f2bf(x0.x); xb[1] = (short)f2bf(x0.y);
    xb[2] = (short)f2bf(x0.z); xb[3] = (short)f2bf(x0.w);
    xb[4] = (short)f2bf(x1.x); xb[5] = (short)f2bf(x1.y);
    xb[6] = (short)f2bf(x1.z); xb[7] = (short)f2bf(x1.w);
    *(bfrag*)&Xs[r * PITCH + k] = xb;
    if (xbf) *(bfrag*)(xbf + (size_t)gr * H + k) = xb;
  }
  __syncthreads();  // the only barrier

  ffrag acc[4][4];
#pragma unroll
  for (int i = 0; i < 4; ++i)
#pragma unroll
    for (int t = 0; t < 4; ++t) acc[i][t] = (ffrag)(0.f);

#pragma unroll
  for (int ks = 0; ks < 8; ++ks) {
    const int k0 = ks * 32;
    bfrag a[4];
#pragma unroll
    for (int i = 0; i < 4; ++i)
      a[i] = *(const bfrag*)&Xs[(16 * i + nidx) * PITCH + k0 + q * 8];
    bfrag bhi[4], blo[4];
#pragma unroll
    for (int t = 0; t < 4; ++t) {
      const size_t off = (size_t)(wave * 64 + t * 16 + nidx) * H + k0 + q * 8;
      bhi[t] = *(const bfrag*)(Whi + off);
      blo[t] = *(const bfrag*)(Wlo + off);
    }
#pragma unroll
    for (int i = 0; i < 4; ++i)
#pragma unroll
      for (int t = 0; t < 4; ++t) {
        acc[i][t] = __builtin_amdgcn_mfma_f32_16x16x32_bf16(a[i], bhi[t], acc[i][t], 0, 0, 0);
        acc[i][t] = __builtin_amdgcn_mfma_f32_16x16x32_bf16(a[i], blo[t], acc[i][t], 0, 0, 0);
      }
  }

  // ---- epilogue: C/D layout col=lane&15, row=q*4+reg; write bf16 ----
#pragma unroll
  for (int i = 0; i < 4; ++i)
#pragma unroll
    for (int r = 0; r < 4; ++r) {
      const int grow = row0 + 16 * i + q * 4 + r;
      if (grow < M) {
#pragma unroll
        for (int t = 0; t < 4; ++t)
          projbf[(size_t)grow * H + wave * 64 + t * 16 + nidx] = f2bf(acc[i][t][r]);
      }
    }
}

// ---------------- fused per-company scores + softmax + aggregate ----------------
__device__ __forceinline__ float fast_tanh(float x) {
  float e = __expf(2.f * x);
  return 1.f - 2.f / (e + 1.f);
}

__global__ __launch_bounds__(256) void edge_kernel(
    const ushort* __restrict__ news_projbf, const ushort* __restrict__ company_projbf,
    const float* __restrict__ v, const int* __restrict__ offsets,
    const int* __restrict__ srcs, float* __restrict__ wsorted,
    const ushort* __restrict__ news_xbf, float* __restrict__ out) {
  const int c = blockIdx.x;
  const int tid = threadIdx.x, lane = tid & 63, wid = tid >> 6;
  __shared__ float cp[H];
  __shared__ float redmax[4], redsum[4];
  cp[tid] = bf2f(company_projbf[(size_t)c * H + tid]);
  __syncthreads();
  const float4 vv = *(const float4*)(v + lane * 4);
  const float4 cq = *(const float4*)&cp[lane * 4];
  const int beg = offsets[c], end = offsets[c + 1];

  // pass 1: one wave per edge-pair (2-unroll for gather ILP)
  float lmax = -INFINITY;
  int i = beg + wid * 2;
  for (; i + 1 < end; i += 8) {
    const int s0 = srcs[i], s1 = srcs[i + 1];
    const ushort4 p0 = *(const ushort4*)(news_projbf + (size_t)s0 * H + lane * 4);
    const ushort4 p1 = *(const ushort4*)(news_projbf + (size_t)s1 * H + lane * 4);
    float pa = fast_tanh(bf2f(p0.x) + cq.x) * vv.x + fast_tanh(bf2f(p0.y) + cq.y) * vv.y +
               fast_tanh(bf2f(p0.z) + cq.z) * vv.z + fast_tanh(bf2f(p0.w) + cq.w) * vv.w;
    float pb = fast_tanh(bf2f(p1.x) + cq.x) * vv.x + fast_tanh(bf2f(p1.y) + cq.y) * vv.y +
               fast_tanh(bf2f(p1.z) + cq.z) * vv.z + fast_tanh(bf2f(p1.w) + cq.w) * vv.w;
#pragma unroll
    for (int off = 32; off > 0; off >>= 1) {
      pa += __shfl_xor(pa, off);
      pb += __shfl_xor(pb, off);
    }
    if (lane == 0) { wsorted[i] = pa; wsorted[i + 1] = pb; }
    lmax = fmaxf(lmax, fmaxf(pa, pb));
  }
  if (i < end) {  // trailing odd edge (at most one wave hits this)
    const int s0 = srcs[i];
    const ushort4 p0 = *(const ushort4*)(news_projbf + (size_t)s0 * H + lane * 4);
    float pa = fast_tanh(bf2f(p0.x) + cq.x) * vv.x + fast_tanh(bf2f(p0.y) + cq.y) * vv.y +
               fast_tanh(bf2f(p0.z) + cq.z) * vv.z + fast_tanh(bf2f(p0.w) + cq.w) * vv.w;
#pragma unroll
    for (int off = 32; off > 0; off >>= 1) pa += __shfl_xor(pa, off);
    if (lane == 0) wsorted[i] = pa;
    lmax = fmaxf(lmax, pa);
  }
  if (lane == 0) redmax[wid] = lmax;
  __syncthreads();
  const float smax = fmaxf(fmaxf(redmax[0], redmax[1]), fmaxf(redmax[2], redmax[3]));

  // pass 2: exp + sum
  float psum = 0.f;
  for (int j = beg + tid; j < end; j += 256) {
    float w = __expf(wsorted[j] - smax);
    wsorted[j] = w;
    psum += w;
  }
#pragma unroll
  for (int off = 32; off > 0; off >>= 1) psum += __shfl_xor(psum, off);
  if (lane == 0) redsum[wid] = psum;
  __syncthreads();
  const float denom = redsum[0] + redsum[1] + redsum[2] + redsum[3];
  const float rden = 1.f / fmaxf(denom, 1e-9f);

  // pass 3: normalize
  for (int j = beg + tid; j < end; j += 256) wsorted[j] *= rden;
  __syncthreads();

  // pass 4: aggregate — thread = column, bf16 news_x gathers (L3-resident)
  float a0 = 0.f, a1 = 0.f;
  int e = beg;
  for (; e + 2 <= end; e += 2) {
    const int s0 = srcs[e], s1 = srcs[e + 1];
    const float w0 = wsorted[e], w1 = wsorted[e + 1];
    a0 = fmaf(w0, bf2f(news_xbf[(size_t)s0 * H + tid]), a0);
    a1 = fmaf(w1, bf2f(news_xbf[(size_t)s1 * H + tid]), a1);
  }
  if (e < end)
    a0 = fmaf(wsorted[e], bf2f(news_xbf[(size_t)srcs[e] * H + tid]), a0);
  out[(size_t)c * H + tid] = a0 + a1;
}

// ---------------- launch ----------------
extern "C" void kernel_launch(void* const* d_in, const int* in_sizes, int n_in,
                              void* d_out, int out_size, void* d_ws, size_t ws_size,
                              hipStream_t stream) {
  const float* news_x    = (const float*)d_in[0];
  const float* company_x = (const float*)d_in[1];
  const float* W_news    = (const float*)d_in[2];
  const float* W_company = (const float*)d_in[3];
  const float* v         = (const float*)d_in[4];
  const int*   src       = (const int*)d_in[5];
  const int*   dst       = (const int*)d_in[6];
  const int N = in_sizes[0] / H;
  const int C = in_sizes[1] / H;
  const int E = in_sizes[5];
  float* out = (float*)d_out;

  char* p = (char*)d_ws;
  ushort* news_projbf    = (ushort*)p; p += (size_t)N * H * sizeof(ushort);
  ushort* news_xbf       = (ushort*)p; p += (size_t)N * H * sizeof(ushort);
  ushort* company_projbf = (ushort*)p; p += (size_t)C * H * sizeof(ushort);
  float*  wsorted        = (float*)p;  p += (size_t)E * sizeof(float);
  int*    srcs_sorted    = (int*)p;    p += (size_t)E * sizeof(int);
  ushort* Wn_hi          = (ushort*)p; p += (size_t)H * H * sizeof(ushort);
  ushort* Wn_lo          = (ushort*)p; p += (size_t)H * H * sizeof(ushort);
  ushort* Wc_hi          = (ushort*)p; p += (size_t)H * H * sizeof(ushort);
  ushort* Wc_lo          = (ushort*)p; p += (size_t)H * H * sizeof(ushort);
  int*    counts         = (int*)p;    p += (size_t)C * sizeof(int);
  int*    offsets        = (int*)p;    p += (size_t)(C + 1) * sizeof(int);
  int*    cursor         = (int*)p;    p += (size_t)C * sizeof(int);

  zero_counts_kernel<<<(C + 255) / 256, 256, 0, stream>>>(counts, C);
  count_kernel<<<(E + 255) / 256, 256, 0, stream>>>(dst, counts, E);
  scan_kernel<<<1, 256, 0, stream>>>(counts, offsets, cursor, C);
  fill_kernel<<<(E + 255) / 256, 256, 0, stream>>>(src, dst, cursor, srcs_sorted, E);

  wsplit_kernel<<<H * H / 256, 256, 0, stream>>>(W_company, Wc_hi, Wc_lo);
  wsplit_kernel<<<H * H / 256, 256, 0, stream>>>(W_news, Wn_hi, Wn_lo);

  gemm_mfma2<<<(C + 63) / 64, 256, 0, stream>>>(company_x, Wc_hi, Wc_lo,
                                                company_projbf, (ushort*)nullptr, C);
  gemm_mfma2<<<(N + 63) / 64, 256, 0, stream>>>(news_x, Wn_hi, Wn_lo,
                                                news_projbf, news_xbf, N);

  edge_kernel<<<C, 256, 0, stream>>>(news_projbf, company_projbf, v, offsets,
                                     srcs_sorted, wsorted, news_xbf, out);
}

// Round 4
// 659.131 us; speedup vs baseline: 1.4590x; 1.0914x over previous
//
#include <hip/hip_runtime.h>
#include <hip/hip_bf16.h>
#include <cmath>
#include <cstdint>

// AttentionPoolingAggregator — MI355X round 4
//  * edge kernel: flash-style single pass (online softmax + fused aggregate),
//    one-ahead software pipeline => 8 gathers in flight per wave.
//  * dispatch count 11 -> 7: counts via hipMemsetAsync; wsplit x2 + histogram
//    fused into one block-range prep kernel.
//  * GEMMs unchanged from round 3 (attribution).

#define H 256

typedef __attribute__((ext_vector_type(8))) short bfrag;  // 8 bf16 (4 VGPRs)
typedef __attribute__((ext_vector_type(4))) float ffrag;  // 4 fp32 acc

__device__ __forceinline__ ushort f2bf(float f) {  // fp32 -> bf16 RNE
  uint u = __float_as_uint(f);
  uint r = u + 0x7FFFu + ((u >> 16) & 1u);
  return (ushort)(r >> 16);
}
__device__ __forceinline__ float bf2f(ushort h) {
  return __uint_as_float((uint)h << 16);
}

// ---------------- prep: wsplit(W_news) | wsplit(W_company) | count histogram ----------------
__global__ void prep_kernel(const float* __restrict__ Wn, const float* __restrict__ Wc,
                            ushort* __restrict__ WnHi, ushort* __restrict__ WnLo,
                            ushort* __restrict__ WcHi, ushort* __restrict__ WcLo,
                            const int* __restrict__ dst, int* __restrict__ counts, int E) {
  const int b = blockIdx.x, tid = threadIdx.x;
  if (b < 256) {
    int i = b * 256 + tid;
    float w = Wn[i];
    ushort h = f2bf(w);
    WnHi[i] = h;
    WnLo[i] = f2bf(w - bf2f(h));
  } else if (b < 512) {
    int i = (b - 256) * 256 + tid;
    float w = Wc[i];
    ushort h = f2bf(w);
    WcHi[i] = h;
    WcLo[i] = f2bf(w - bf2f(h));
  } else {
    int e = (b - 512) * 256 + tid;
    if (e < E) atomicAdd(&counts[dst[e]], 1);
  }
}

// single-block scan over C counts -> exclusive offsets[0..C], cursor copy
__global__ void scan_kernel(const int* __restrict__ counts, int* __restrict__ offsets,
                            int* __restrict__ cursor, int C) {
  __shared__ int wsum[4];
  int tid = threadIdx.x;
  int lane = tid & 63, wid = tid >> 6;
  int base = 0;
  for (int start = 0; start < C; start += 256) {
    int idx = start + tid;
    int val = (idx < C) ? counts[idx] : 0;
    int x = val;
#pragma unroll
    for (int off = 1; off < 64; off <<= 1) {
      int y = __shfl_up(x, off);
      if (lane >= off) x += y;
    }
    if (lane == 63) wsum[wid] = x;
    __syncthreads();
    int add = base;
    for (int w = 0; w < wid; ++w) add += wsum[w];
    if (idx < C) {
      int excl = add + x - val;
      offsets[idx] = excl;
      cursor[idx]  = excl;
    }
    int tot = wsum[0] + wsum[1] + wsum[2] + wsum[3];
    __syncthreads();
    base += tot;
  }
  if (tid == 0) offsets[C] = base;
}

__global__ void fill_kernel(const int* __restrict__ src, const int* __restrict__ dst,
                            int* __restrict__ cursor, int* __restrict__ srcs_sorted, int E) {
  int e = blockIdx.x * blockDim.x + threadIdx.x;
  if (e < E) {
    int d = dst[e];
    int pos = atomicAdd(&cursor[d], 1);
    srcs_sorted[pos] = src[e];
  }
}

// ---------------- MFMA GEMM (unchanged from round 3) ----------------
__global__ __launch_bounds__(256, 2) void gemm_mfma2(
    const float* __restrict__ X, const ushort* __restrict__ Whi,
    const ushort* __restrict__ Wlo, ushort* __restrict__ projbf,
    ushort* __restrict__ xbf, int M) {
  constexpr int PITCH = 264;           // ushorts per LDS row (528B = 33*16B)
  __shared__ ushort Xs[64 * PITCH];    // 33.8 KB
  const int tid = threadIdx.x;
  const int wave = tid >> 6, lane = tid & 63;
  const int q = lane >> 4, nidx = lane & 15;
  const int row0 = blockIdx.x * 64;

#pragma unroll
  for (int it = 0; it < 8; ++it) {
    const int flat = it * 2048 + tid * 8;
    const int r = flat >> 8, k = flat & 255;
    int gr = row0 + r;
    if (gr >= M) gr = M - 1;
    const float4 x0 = *(const float4*)(X + (size_t)gr * H + k);
    const float4 x1 = *(const float4*)(X + (size_t)gr * H + k + 4);
    bfrag xb;
    xb[0] = (short)f2bf(x0.x); xb[1] = (short)f2bf(x0.y);
    xb[2] = (short)f2bf(x0.z); xb[3] = (short)f2bf(x0.w);
    xb[4] = (short)f2bf(x1.x); xb[5] = (short)f2bf(x1.y);
    xb[6] = (short)f2bf(x1.z); xb[7] = (short)f2bf(x1.w);
    *(bfrag*)&Xs[r * PITCH + k] = xb;
    if (xbf) *(bfrag*)(xbf + (size_t)gr * H + k) = xb;
  }
  __syncthreads();  // the only barrier

  ffrag acc[4][4];
#pragma unroll
  for (int i = 0; i < 4; ++i)
#pragma unroll
    for (int t = 0; t < 4; ++t) acc[i][t] = (ffrag)(0.f);

#pragma unroll
  for (int ks = 0; ks < 8; ++ks) {
    const int k0 = ks * 32;
    bfrag a[4];
#pragma unroll
    for (int i = 0; i < 4; ++i)
      a[i] = *(const bfrag*)&Xs[(16 * i + nidx) * PITCH + k0 + q * 8];
    bfrag bhi[4], blo[4];
#pragma unroll
    for (int t = 0; t < 4; ++t) {
      const size_t off = (size_t)(wave * 64 + t * 16 + nidx) * H + k0 + q * 8;
      bhi[t] = *(const bfrag*)(Whi + off);
      blo[t] = *(const bfrag*)(Wlo + off);
    }
#pragma unroll
    for (int i = 0; i < 4; ++i)
#pragma unroll
      for (int t = 0; t < 4; ++t) {
        acc[i][t] = __builtin_amdgcn_mfma_f32_16x16x32_bf16(a[i], bhi[t], acc[i][t], 0, 0, 0);
        acc[i][t] = __builtin_amdgcn_mfma_f32_16x16x32_bf16(a[i], blo[t], acc[i][t], 0, 0, 0);
      }
  }

#pragma unroll
  for (int i = 0; i < 4; ++i)
#pragma unroll
    for (int r = 0; r < 4; ++r) {
      const int grow = row0 + 16 * i + q * 4 + r;
      if (grow < M) {
#pragma unroll
        for (int t = 0; t < 4; ++t)
          projbf[(size_t)grow * H + wave * 64 + t * 16 + nidx] = f2bf(acc[i][t][r]);
      }
    }
}

// ---------------- fused flash edge kernel: scores + online softmax + aggregate ----------------
__device__ __forceinline__ float fast_tanh(float x) {
  float e = __expf(2.f * x);
  return 1.f - 2.f / (e + 1.f);
}

// tanh(p + cq) . vv over this lane's 4 cols, then 64-lane butterfly sum
__device__ __forceinline__ float score_dot(ushort4 p, float4 cq, float4 vv) {
  float r = fast_tanh(bf2f(p.x) + cq.x) * vv.x + fast_tanh(bf2f(p.y) + cq.y) * vv.y +
            fast_tanh(bf2f(p.z) + cq.z) * vv.z + fast_tanh(bf2f(p.w) + cq.w) * vv.w;
#pragma unroll
  for (int off = 32; off > 0; off >>= 1) r += __shfl_xor(r, off);
  return r;  // all lanes hold the total
}

__global__ __launch_bounds__(256) void edge_flash_kernel(
    const ushort* __restrict__ news_projbf, const ushort* __restrict__ company_projbf,
    const float* __restrict__ v, const int* __restrict__ offsets,
    const int* __restrict__ srcs, const ushort* __restrict__ news_xbf,
    float* __restrict__ out) {
  const int c = blockIdx.x;
  const int tid = threadIdx.x, lane = tid & 63, wid = tid >> 6;
  __shared__ float cp[H];
  __shared__ float mW[4], lW[4];
  __shared__ float OW[4][H];  // 4 KB
  cp[tid] = bf2f(company_projbf[(size_t)c * H + tid]);
  __syncthreads();
  const float4 vv = *(const float4*)(v + lane * 4);
  const float4 cq = *(const float4*)&cp[lane * 4];
  const int beg = offsets[c], end = offsets[c + 1];

  float m = -INFINITY, l = 0.f;
  float4 O = make_float4(0.f, 0.f, 0.f, 0.f);

  // ---- pipelined pair loop: wave handles edges (beg+2*wid + 8k, +1) ----
  int i = beg + wid * 2;
  if (i + 1 < end) {
    int s0 = srcs[i], s1 = srcs[i + 1];
    ushort4 p0 = *(const ushort4*)(news_projbf + (size_t)s0 * H + lane * 4);
    ushort4 p1 = *(const ushort4*)(news_projbf + (size_t)s1 * H + lane * 4);
    ushort4 x0 = *(const ushort4*)(news_xbf + (size_t)s0 * H + lane * 4);
    ushort4 x1 = *(const ushort4*)(news_xbf + (size_t)s1 * H + lane * 4);
    for (;;) {
      const int inext = i + 8;
      const bool more = (inext + 1 < end);  // wave-uniform
      ushort4 np0, np1, nx0, nx1;
      if (more) {  // prefetch next pair while computing current
        int t0 = srcs[inext], t1 = srcs[inext + 1];
        np0 = *(const ushort4*)(news_projbf + (size_t)t0 * H + lane * 4);
        np1 = *(const ushort4*)(news_projbf + (size_t)t1 * H + lane * 4);
        nx0 = *(const ushort4*)(news_xbf + (size_t)t0 * H + lane * 4);
        nx1 = *(const ushort4*)(news_xbf + (size_t)t1 * H + lane * 4);
      }
      const float sa = score_dot(p0, cq, vv);
      const float sb = score_dot(p1, cq, vv);
      const float mnew = fmaxf(m, fmaxf(sa, sb));
      const float alpha = __expf(m - mnew);  // first iter: exp(-inf)=0
      const float pa = __expf(sa - mnew);
      const float pb = __expf(sb - mnew);
      l = l * alpha + pa + pb;
      O.x = O.x * alpha + pa * bf2f(x0.x) + pb * bf2f(x1.x);
      O.y = O.y * alpha + pa * bf2f(x0.y) + pb * bf2f(x1.y);
      O.z = O.z * alpha + pa * bf2f(x0.z) + pb * bf2f(x1.z);
      O.w = O.w * alpha + pa * bf2f(x0.w) + pb * bf2f(x1.w);
      m = mnew;
      i = inext;
      if (!more) break;
      p0 = np0; p1 = np1; x0 = nx0; x1 = nx1;
    }
  }
  if (i < end) {  // trailing single edge
    const int s0 = srcs[i];
    const ushort4 p0 = *(const ushort4*)(news_projbf + (size_t)s0 * H + lane * 4);
    const ushort4 x0 = *(const ushort4*)(news_xbf + (size_t)s0 * H + lane * 4);
    const float sa = score_dot(p0, cq, vv);
    const float mnew = fmaxf(m, sa);
    const float alpha = __expf(m - mnew);
    const float pa = __expf(sa - mnew);
    l = l * alpha + pa;
    O.x = O.x * alpha + pa * bf2f(x0.x);
    O.y = O.y * alpha + pa * bf2f(x0.y);
    O.z = O.z * alpha + pa * bf2f(x0.z);
    O.w = O.w * alpha + pa * bf2f(x0.w);
    m = mnew;
  }

  // ---- merge 4 waves ----
  if (lane == 0) { mW[wid] = m; lW[wid] = l; }
  *(float4*)&OW[wid][lane * 4] = O;
  __syncthreads();
  const float mstar = fmaxf(fmaxf(mW[0], mW[1]), fmaxf(mW[2], mW[3]));
  float denom = 0.f, val = 0.f;
#pragma unroll
  for (int w = 0; w < 4; ++w) {
    const float sc = (lW[w] > 0.f) ? __expf(mW[w] - mstar) : 0.f;
    denom += lW[w] * sc;
    val += OW[w][tid] * sc;
  }
  out[(size_t)c * H + tid] = val / fmaxf(denom, 1e-9f);
}

// ---------------- launch ----------------
extern "C" void kernel_launch(void* const* d_in, const int* in_sizes, int n_in,
                              void* d_out, int out_size, void* d_ws, size_t ws_size,
                              hipStream_t stream) {
  const float* news_x    = (const float*)d_in[0];
  const float* company_x = (const float*)d_in[1];
  const float* W_news    = (const float*)d_in[2];
  const float* W_company = (const float*)d_in[3];
  const float* v         = (const float*)d_in[4];
  const int*   src       = (const int*)d_in[5];
  const int*   dst       = (const int*)d_in[6];
  const int N = in_sizes[0] / H;
  const int C = in_sizes[1] / H;
  const int E = in_sizes[5];
  float* out = (float*)d_out;

  char* p = (char*)d_ws;
  ushort* news_projbf    = (ushort*)p; p += (size_t)N * H * sizeof(ushort);
  ushort* news_xbf       = (ushort*)p; p += (size_t)N * H * sizeof(ushort);
  ushort* company_projbf = (ushort*)p; p += (size_t)C * H * sizeof(ushort);
  int*    srcs_sorted    = (int*)p;    p += (size_t)E * sizeof(int);
  ushort* Wn_hi          = (ushort*)p; p += (size_t)H * H * sizeof(ushort);
  ushort* Wn_lo          = (ushort*)p; p += (size_t)H * H * sizeof(ushort);
  ushort* Wc_hi          = (ushort*)p; p += (size_t)H * H * sizeof(ushort);
  ushort* Wc_lo          = (ushort*)p; p += (size_t)H * H * sizeof(ushort);
  int*    counts         = (int*)p;    p += (size_t)C * sizeof(int);
  int*    offsets        = (int*)p;    p += (size_t)(C + 1) * sizeof(int);
  int*    cursor         = (int*)p;    p += (size_t)C * sizeof(int);

  hipMemsetAsync(counts, 0, (size_t)C * sizeof(int), stream);
  prep_kernel<<<512 + (E + 255) / 256, 256, 0, stream>>>(
      W_news, W_company, Wn_hi, Wn_lo, Wc_hi, Wc_lo, dst, counts, E);
  scan_kernel<<<1, 256, 0, stream>>>(counts, offsets, cursor, C);
  fill_kernel<<<(E + 255) / 256, 256, 0, stream>>>(src, dst, cursor, srcs_sorted, E);

  gemm_mfma2<<<(C + 63) / 64, 256, 0, stream>>>(company_x, Wc_hi, Wc_lo,
                                                company_projbf, (ushort*)nullptr, C);
  gemm_mfma2<<<(N + 63) / 64, 256, 0, stream>>>(news_x, Wn_hi, Wn_lo,
                                                news_projbf, news_xbf, N);

  edge_flash_kernel<<<C, 256, 0, stream>>>(news_projbf, company_projbf, v, offsets,
                                           srcs_sorted, news_xbf, out);
}